// Round 18
// baseline (2486.362 us; speedup 1.0000x reference)
//
#include <hip/hip_runtime.h>

#define AD 128
#define BDW 128
#define ZD 16
#define NVOX (AD*BDW*ZD)   // 262144
#define SLAB 65536         // 32 a-rows per slab
#define NSLAB 4
#define NRING 4            // ring slots (occ2(s-2) runs beside occ1(s))

typedef __attribute__((ext_vector_type(4))) float f32x4;
typedef __attribute__((ext_vector_type(8))) short bf16x8;
typedef __attribute__((ext_vector_type(8))) short s16x8;

__device__ __forceinline__ float leaky(float v) { return v > 0.f ? v : 0.01f * v; }

__device__ __forceinline__ f32x4 mfma16(bf16x8 a, bf16x8 b, f32x4 c) {
    return __builtin_amdgcn_mfma_f32_16x16x32_bf16(a, b, c, 0, 0, 0);
}

// Exact 3-way bf16 split of fp32: v = h1 + h2 + h3 (bit-truncation, exact).
__device__ __forceinline__ void split3(float v, unsigned short& s1,
                                       unsigned short& s2, unsigned short& s3) {
    const unsigned u1 = __float_as_uint(v) & 0xFFFF0000u;
    const float r1 = v - __uint_as_float(u1);
    const unsigned u2 = __float_as_uint(r1) & 0xFFFF0000u;
    const float r2 = r1 - __uint_as_float(u2);
    s1 = (unsigned short)(u1 >> 16);
    s2 = (unsigned short)(u2 >> 16);
    s3 = (unsigned short)(__float_as_uint(r2) >> 16);
}

// LDS A-plane addressing (halves): row = halo voxel (32 halves), 16B-slot XOR
// swizzle: slot(v,chunk) = (4v+chunk) ^ (v&7) -> 2-way max on write & read.
__device__ __forceinline__ int lds_a_off(int v, int chunk) {
    return ((v << 5) + (chunk << 3)) ^ ((v & 7) << 3);
}

// ---------------------------------------------------------------------------
// Fused weight 3-split for all three convs:
// w[oc][128][27] fp32 -> 3 planes of [27][4kb][4kc][OC][8] bf16.
__global__ __launch_bounds__(256) void wsplit_all(const float* __restrict__ wb,
                                                  const float* __restrict__ wo,
                                                  const float* __restrict__ wsd,
                                                  unsigned short* __restrict__ WB,
                                                  unsigned short* __restrict__ WO,
                                                  unsigned short* __restrict__ WS) {
    int blk = blockIdx.x;
    const float* src; unsigned short* dst; int OC;
    if (blk < 1728)      { src = wb;  dst = WB; OC = 128; }
    else if (blk < 2592) { src = wo;  dst = WO; OC = 64; blk -= 1728; }
    else                 { src = wsd; dst = WS; OC = 64; blk -= 2592; }
    const int i = blk * 256 + threadIdx.x;
    const int PS = OC * 3456;
    if (i >= PS) return;
    const int ko = i & 7;
    const int oc = (i >> 3) % OC;
    const int rest = (i >> 3) / OC;      // (t*4+kb)*4 + kc
    const int kc = rest & 3;
    const int kbt = rest >> 2;           // t*4+kb
    const int kb = kbt & 3, t = kbt >> 2;
    const int ic = kb * 32 + kc * 8 + ko;
    const float v = src[((size_t)oc * 128 + ic) * 27 + t];
    unsigned short s1, s2, s3;
    split3(v, s1, s2, s3);
    dst[i] = s1; dst[i + PS] = s2; dst[i + 2 * PS] = s3;
}

// ---------------------------------------------------------------------------
// occ2 block role (1024 thr): mask conv 64->2 as logit-DIFF over the ring.
// Tile 4a x 4b x 16z = 256 vox; halo 648 rows; 2 x 32-ic rounds.
__device__ void occ2_role(const float* __restrict__ HR,
                          const float* __restrict__ w,
                          const float* __restrict__ b,
                          unsigned char* __restrict__ mask,
                          int bx2raw, int sp_base, unsigned short* smraw) {
    const int grp = bx2raw >> 8;               // slab offset within this dispatch
    const int r   = bx2raw & 255;
    const int bx  = (r & 7) * 32 + (r >> 3);   // XCD swizzle within 256
    const int sp  = sp_base + grp;

    float* hl  = (float*)smraw;                // [648][36]  93312 B
    float* wl  = hl + 648 * 36;                // [1728]
    float* red = wl + 1728;                    // [4][260]

    const int tid = threadIdx.x;
    for (int i = tid; i < 1728; i += 1024) wl[i] = w[1728 + i] - w[i];

    const int a0 = sp * 32 + (bx >> 5) * 4;
    const int b0 = (bx & 31) * 4;
    const int g = tid >> 8, v = tid & 255;
    const int a_l = v >> 6, b_l = (v >> 4) & 3, z = v & 15;

    float acc0 = 0.f, acc1 = 0.f;
    #pragma unroll 1
    for (int half = 0; half < 2; ++half) {
        __syncthreads();
        for (int i = tid; i < 5184; i += 1024) {
            const int q4 = i / 648;
            const int hv = i - q4 * 648;
            const int col = hv / 18;
            const int zz  = hv - col * 18;
            const int ha  = col / 6;
            const int hb  = col - ha * 6;
            const int a = a0 + ha - 1;
            const int bb = b0 + hb - 1;
            const int zq = zz - 1;
            f32x4 val = {0.f, 0.f, 0.f, 0.f};
            if (((unsigned)a < 128u) && ((unsigned)bb < 128u) && ((unsigned)zq < 16u)) {
                const int q = a * 2048 + bb * 16 + zq;
                const int rc = ((a >> 5) & (NRING - 1)) * SLAB + (q & (SLAB - 1));
                const int ic0 = half * 32 + q4 * 4;
                #pragma unroll
                for (int j = 0; j < 4; ++j)
                    val[j] = HR[(size_t)(ic0 + j) * (NRING * SLAB) + rc];
            }
            *(f32x4*)(hl + hv * 36 + q4 * 4) = val;
        }
        __syncthreads();
        #pragma unroll 1
        for (int t = 0; t < 27; ++t) {
            const int ta = t / 9, tb = (t / 3) % 3, tz = t % 3;
            const int vt = ((a_l + ta) * 6 + b_l + tb) * 18 + z + tz;
            #pragma unroll
            for (int j = 0; j < 8; j += 2) {
                const int icl = g * 8 + j;
                const int ic = half * 32 + icl;
                acc0 = fmaf(hl[vt * 36 + icl],     wl[ic * 27 + t],       acc0);
                acc1 = fmaf(hl[vt * 36 + icl + 1], wl[(ic + 1) * 27 + t], acc1);
            }
        }
    }
    red[g * 260 + v] = acc0 + acc1;
    __syncthreads();
    if (g == 0) {
        float t0 = b[1] - b[0];
        #pragma unroll
        for (int k = 0; k < 4; ++k) t0 += red[k * 260 + v];
        mask[(a0 + a_l) * 2048 + (b0 + b_l) * 16 + z] = (t0 > 0.f) ? 1 : 0;
    }
}

// ---------------------------------------------------------------------------
// fp32-grade 3x3x3 conv via bf16-split 16x16x32 MFMA (R15 structure).
// PROD=6: 3 planes (mask path). PROD=3: 2 planes (post-mask path).
// FUSEOCC2: blocks >= occ1_grid run the occ2 mask role instead.
// Tap loop flattened tt=0..8 with #pragma unroll 2: gives the scheduler a
// 2-iteration region for cross-iteration load/MFMA overlap WITHOUT R13's
// full-unroll register blow-up (spill signature: FETCH >> 185 MB).
template<int OC, int PROD, int AQ, bool PREMUL, bool LEAKY, int RING,
         bool FUSESSC, bool FUSEOCC2>
__global__ __launch_bounds__(AQ * 256, 1) void conv3s(const float* __restrict__ src,
                                              const float* __restrict__ prob,
                                              const unsigned short* __restrict__ W,
                                              const float* __restrict__ bias,
                                              float* __restrict__ out,
                                              const float* __restrict__ wssc,
                                              const float* __restrict__ bssc,
                                              unsigned char* __restrict__ maskp,
                                              int occ1_grid, int sp_base,
                                              int ablk_base) {
    constexpr int THREADS = AQ * 256;
    constexpr int NPL = (PROD == 6) ? 3 : 2;
    constexpr int HROWS = (AQ + 2) * 108;          // halo rows
    constexpr int PLH = HROWS * 32;                // plane size in halves
    constexpr int VOXT = AQ * 64;                  // output voxels per block
    constexpr int NITEM = HROWS * 4;               // staging items (row x ic-oct)
    constexpr int PFI = (NITEM + THREADS - 1) / THREADS;
    constexpr int EPIH = OC * (VOXT + 1) * 2;      // epilogue halves
    constexpr int SMH = (NPL * PLH > EPIH) ? NPL * PLH : EPIH;
    __shared__ __align__(16) unsigned short smraw[SMH];
    unsigned short* sm0 = smraw;
    unsigned short* sm1 = smraw + PLH;
    unsigned short* sm2 = smraw + (NPL - 1) * PLH; // ==sm1 when NPL==2 (unused)

    if (FUSEOCC2 && (int)blockIdx.x >= occ1_grid) {
        occ2_role(out, wssc, bssc, maskp, (int)blockIdx.x - occ1_grid,
                  sp_base, smraw);
        return;
    }

    const int tid = threadIdx.x;
    // bijective XCD swizzle over the conv-role grid
    const int cg = FUSEOCC2 ? occ1_grid : (int)gridDim.x;
    const int cpx = cg >> 3;
    const int bx = ((int)blockIdx.x & 7) * cpx + ((int)blockIdx.x >> 3);

    const int ablkA = ablk_base + (bx >> 5);       // AQ-a-row tile index
    const int b0    = (bx & 31) * 4;
    const int vbase = ablkA * (AQ * 2048) + b0 * 16;

    const int w = tid >> 6, l = tid & 63;
    const int lo16 = l & 15, hi4 = l >> 4;
    const int wo = w & 3, wm = w >> 2;
    constexpr int NF = OC / 64;                    // 128 -> 2, 64 -> 1
    constexpr int PS = OC * 3456;
    const int oc_off = wo * (16 * NF);

    f32x4 acc[4][NF];
    #pragma unroll
    for (int nf = 0; nf < NF; ++nf) {
        const float bv = bias[oc_off + nf * 16 + lo16];
        #pragma unroll
        for (int mf = 0; mf < 4; ++mf) acc[mf][nf] = f32x4{bv, bv, bv, bv};
    }

    // ---- prefetch registers (issue-early / write-late pipeline) ----
    float pf[PFI][8];
    float pfpm[PFI];

    #define PREFETCH(KB)                                                          \
        _Pragma("unroll")                                                         \
        for (int it = 0; it < PFI; ++it) {                                        \
            const int i = tid + it * THREADS;                                     \
            _Pragma("unroll")                                                     \
            for (int j = 0; j < 8; ++j) pf[it][j] = 0.f;                          \
            pfpm[it] = 1.f;                                                       \
            if (i < NITEM) {                                                      \
                const int q8 = i / HROWS;                                         \
                const int v  = i - q8 * HROWS;                                    \
                const int col = v / 18;                                           \
                const int zz  = v - col * 18;                                     \
                const int ha  = col / 6;                                          \
                const int hb  = col - ha * 6;                                     \
                const int a = ablkA * AQ + ha - 1;                                \
                const int b = b0 + hb - 1;                                        \
                const int z = zz - 1;                                             \
                if (((unsigned)a < 128u) && ((unsigned)b < 128u) &&               \
                    ((unsigned)z < 16u)) {                                        \
                    const int q = a * 2048 + b * 16 + z;                          \
                    const float* sp = src + (size_t)((KB) * 32 + q8 * 8) * NVOX + q; \
                    _Pragma("unroll")                                             \
                    for (int j = 0; j < 8; ++j) pf[it][j] = sp[(size_t)j * NVOX]; \
                    if (PREMUL) pfpm[it] = 1.f + prob[q];                         \
                }                                                                 \
            }                                                                     \
        }

    PREFETCH(0)

    #pragma unroll 1
    for (int kb = 0; kb < 4; ++kb) {
        __syncthreads();
        // write-late: split3 + swizzled b128 ds_write of the prefetched tile
        #pragma unroll
        for (int it = 0; it < PFI; ++it) {
            const int i = tid + it * THREADS;
            if (i < NITEM) {
                const int q8 = i / HROWS;
                const int v  = i - q8 * HROWS;
                s16x8 t1, t2, t3;
                #pragma unroll
                for (int j = 0; j < 8; ++j) {
                    float f = pf[it][j];
                    if (PREMUL) f *= pfpm[it];
                    unsigned short s1, s2, s3;
                    split3(f, s1, s2, s3);
                    t1[j] = (short)s1; t2[j] = (short)s2; t3[j] = (short)s3;
                }
                const int off = lds_a_off(v, q8);
                *(s16x8*)(sm0 + off) = t1;
                *(s16x8*)(sm1 + off) = t2;
                if (NPL == 3) *(s16x8*)(sm2 + off) = t3;
            }
        }
        if (kb < 3) PREFETCH(kb + 1)
        __syncthreads();

        #pragma unroll 2
        for (int tt = 0; tt < 9; ++tt) {
            const int ta = tt / 3;
            const int tz = tt - ta * 3;
            // 6 shared A-fragments (s = mf+tb) for this wave's a-row
            bf16x8 A1[6], A2[6], A3[6];
            #pragma unroll
            for (int s = 0; s < 6; ++s) {
                const int v = ((wm + ta) * 6 + s) * 18 + lo16 + tz;
                const int ao = lds_a_off(v, hi4);
                A1[s] = *(const bf16x8*)(sm0 + ao);
                A2[s] = *(const bf16x8*)(sm1 + ao);
                if (PROD == 6) A3[s] = *(const bf16x8*)(sm2 + ao);
            }
            #pragma unroll
            for (int tb = 0; tb < 3; ++tb) {
                const int t = ta * 9 + tb * 3 + tz;
                bf16x8 b1[NF], b2[NF], b3[NF];
                #pragma unroll
                for (int nf = 0; nf < NF; ++nf) {
                    const size_t wb = (((size_t)(t * 4 + kb) * 4 + hi4) * OC
                                       + oc_off + nf * 16 + lo16) * 8;
                    b1[nf] = *(const bf16x8*)(W + wb);
                    b2[nf] = *(const bf16x8*)(W + PS + wb);
                    if (PROD == 6) b3[nf] = *(const bf16x8*)(W + 2 * PS + wb);
                }
                #pragma unroll
                for (int mf = 0; mf < 4; ++mf) {
                    const int s = mf + tb;          // static after unroll
                    #pragma unroll
                    for (int nf = 0; nf < NF; ++nf) {
                        acc[mf][nf] = mfma16(A1[s], b1[nf], acc[mf][nf]);
                        acc[mf][nf] = mfma16(A1[s], b2[nf], acc[mf][nf]);
                        acc[mf][nf] = mfma16(A2[s], b1[nf], acc[mf][nf]);
                    }
                    if (PROD == 6) {
                        #pragma unroll
                        for (int nf = 0; nf < NF; ++nf) {
                            acc[mf][nf] = mfma16(A2[s], b2[nf], acc[mf][nf]);
                            acc[mf][nf] = mfma16(A1[s], b3[nf], acc[mf][nf]);
                            acc[mf][nf] = mfma16(A3[s], b1[nf], acc[mf][nf]);
                        }
                    }
                }
            }
        }
    }
    #undef PREFETCH

    // epilogue: leaky -> ldsT[oc][VOXT+1] transpose (stride odd -> conflict-free)
    __syncthreads();
    float* ldsT = (float*)smraw;
    #pragma unroll
    for (int mf = 0; mf < 4; ++mf)
        #pragma unroll
        for (int nf = 0; nf < NF; ++nf) {
            const int oc = oc_off + nf * 16 + lo16;
            #pragma unroll
            for (int r = 0; r < 4; ++r) {
                float vv = acc[mf][nf][r];
                if (LEAKY) vv = leaky(vv);
                // C/D 16x16: col=l&15(oc), row=(l>>4)*4+r; tile vox = wm*64+mf*16+row
                ldsT[oc * (VOXT + 1) + wm * 64 + mf * 16 + hi4 * 4 + r] = vv;
            }
        }
    __syncthreads();
    if (FUSESSC) {
        // 1x1 conv 64->20 from LDS, write [20][NVOX]
        for (int i = tid; i < 20 * VOXT; i += THREADS) {
            const int tv = i % VOXT;
            const int o = i / VOXT;         // wave-uniform (VOXT multiple of 64)
            float acc2 = bssc[o];
            #pragma unroll
            for (int ic = 0; ic < 64; ++ic)
                acc2 = fmaf(ldsT[ic * (VOXT + 1) + tv], wssc[o * 64 + ic], acc2);
            out[(size_t)o * NVOX + vbase + (tv >> 6) * 2048 + (tv & 63)] = acc2;
        }
    } else {
        int obase;
        if (RING == 0) obase = vbase;
        else           obase = ((vbase >> 16) & (NRING - 1)) * SLAB + (vbase & (SLAB - 1));
        const size_t outN = (RING == 0) ? (size_t)NVOX : (size_t)(NRING * SLAB);
        for (int i = tid; i < OC * VOXT; i += THREADS) {
            const int oc = i / VOXT, tv = i % VOXT;
            out[(size_t)oc * outN + obase + (tv >> 6) * 2048 + (tv & 63)] =
                ldsT[oc * (VOXT + 1) + tv];
        }
    }
}

// ---------------------------------------------------------------------------
// Per-voxel MLP prior + masked select, in-place over x ([128][N] f32)
__global__ __launch_bounds__(256) void mlp_vox(float* __restrict__ x,
                                               const float* __restrict__ w1,
                                               const float* __restrict__ b1,
                                               const float* __restrict__ g,
                                               const float* __restrict__ beta,
                                               const float* __restrict__ w2,
                                               const float* __restrict__ b2,
                                               const unsigned char* __restrict__ mask) {
    const int p = blockIdx.x * 256 + threadIdx.x;
    float h[64];
    #pragma unroll
    for (int j = 0; j < 64; ++j) h[j] = b1[j];
    #pragma unroll 1
    for (int c = 0; c < 128; ++c) {
        const float xv = x[(size_t)c * NVOX + p];
        #pragma unroll
        for (int j = 0; j < 64; ++j) h[j] = fmaf(xv, w1[c * 64 + j], h[j]);
    }
    float mu = 0.f;
    #pragma unroll
    for (int j = 0; j < 64; ++j) mu += h[j];
    mu *= (1.f / 64.f);
    float var = 0.f;
    #pragma unroll
    for (int j = 0; j < 64; ++j) { const float d = h[j] - mu; var = fmaf(d, d, var); }
    var *= (1.f / 64.f);
    const float rs = rsqrtf(var + 1e-5f);
    #pragma unroll
    for (int j = 0; j < 64; ++j) h[j] = leaky((h[j] - mu) * rs * g[j] + beta[j]);

    const bool m = mask[p] != 0;
    #pragma unroll 1
    for (int c = 0; c < 128; ++c) {
        float pr = b2[c];
        #pragma unroll
        for (int j = 0; j < 64; ++j) pr = fmaf(h[j], w2[j * 128 + c], pr);
        const size_t idx = (size_t)c * NVOX + p;
        x[idx] = m ? x[idx] : pr;
    }
}

// ---------------------------------------------------------------------------
extern "C" void kernel_launch(void* const* d_in, const int* in_sizes, int n_in,
                              void* d_out, int out_size, void* d_ws, size_t ws_size,
                              hipStream_t stream) {
    const float* x3d    = (const float*)d_in[0];
    const float* prob   = (const float*)d_in[1];
    const float* w_bot  = (const float*)d_in[2];
    const float* b_bot  = (const float*)d_in[3];
    const float* w_occ1 = (const float*)d_in[4];
    const float* b_occ1 = (const float*)d_in[5];
    const float* w_occ2 = (const float*)d_in[6];
    const float* b_occ2 = (const float*)d_in[7];
    const float* w_mlp1 = (const float*)d_in[8];
    const float* b_mlp1 = (const float*)d_in[9];
    const float* ln_g   = (const float*)d_in[10];
    const float* ln_b   = (const float*)d_in[11];
    const float* w_mlp2 = (const float*)d_in[12];
    const float* b_mlp2 = (const float*)d_in[13];
    const float* w_sdb  = (const float*)d_in[14];
    const float* b_sdb  = (const float*)d_in[15];
    const float* w_ssc  = (const float*)d_in[16];
    const float* b_ssc  = (const float*)d_in[17];

    char* ws = (char*)d_ws;
    float* X32 = (float*)(ws);                                 // [128][N] f32, 134.2 MB
    float* HR  = (float*)(ws + 134217728);                     // [64][4*SLAB] f32 ring, 67.1 MB
    unsigned short* WB3 = (unsigned short*)(ws + 201326592);   // 2654208 B
    unsigned short* W13 = (unsigned short*)(ws + 203980800);   // 1327104 B
    unsigned short* WS3 = (unsigned short*)(ws + 205307904);   // 1327104 B
    unsigned char* mask = (unsigned char*)(ws + 206635008);    // 262144 B

    const dim3 blk(256);
    const dim3 blk10(1024);

    // fused weight split (1 dispatch)
    wsplit_all<<<3456, blk, 0, stream>>>(w_bot, w_occ1, w_sdb, WB3, W13, WS3);

    // 1) bottleneck conv 128->128 (6-product, AQ=4) : x3d -> X32
    conv3s<128, 6, 4, false, false, 0, false, false><<<1024, blk10, 0, stream>>>(
        x3d, nullptr, WB3, b_bot, X32, nullptr, nullptr, nullptr, 0, 0, 0);

    // 2/3) occ conv1 (premul, 6-product, AQ=4) per slab into 4-slot ring;
    // occ2(s-2) blocks fused into occ1(s) dispatches; tail handles slabs 2,3.
    for (int s = 0; s < NSLAB; ++s) {
        const int grid = (s >= 2) ? 512 : 256;
        conv3s<64, 6, 4, true, true, 2, false, true><<<grid, blk10, 0, stream>>>(
            X32, prob, W13, b_occ1, HR, w_occ2, b_occ2, mask, 256, s - 2, 8 * s);
    }
    // tail: occ2 for slabs 2 and 3 in one dispatch (all blocks occ2 role)
    conv3s<64, 6, 4, true, true, 2, false, true><<<512, blk10, 0, stream>>>(
        X32, prob, W13, b_occ1, HR, w_occ2, b_occ2, mask, 0, 2, 0);

    // 4) MLP prior + masked select, in-place on X32
    mlp_vox<<<1024, blk, 0, stream>>>(X32, w_mlp1, b_mlp1, ln_g, ln_b, w_mlp2, b_mlp2, mask);

    // 5/6) SDB conv (3-product, AQ=4) + fused SSC head -> d_out [20][N] f32
    conv3s<64, 3, 4, false, true, 0, true, false><<<1024, blk10, 0, stream>>>(
        X32, nullptr, WS3, b_sdb, (float*)d_out, w_ssc, b_ssc, nullptr, 0, 0, 0);
}

// Round 19
// 2167.080 us; speedup vs baseline: 1.1473x; 1.1473x over previous
//
#include <hip/hip_runtime.h>

#define AD 128
#define BDW 128
#define ZD 16
#define NVOX (AD*BDW*ZD)   // 262144
#define SLAB 65536         // 32 a-rows per slab
#define NSLAB 4
#define NRING 4            // ring slots (occ2(s-2) runs beside occ1(s))

typedef __attribute__((ext_vector_type(4))) float f32x4;
typedef __attribute__((ext_vector_type(8))) short bf16x8;
typedef __attribute__((ext_vector_type(8))) short s16x8;

__device__ __forceinline__ float leaky(float v) { return v > 0.f ? v : 0.01f * v; }

__device__ __forceinline__ f32x4 mfma16(bf16x8 a, bf16x8 b, f32x4 c) {
    return __builtin_amdgcn_mfma_f32_16x16x32_bf16(a, b, c, 0, 0, 0);
}

// Exact 3-way bf16 split of fp32: v = h1 + h2 + h3 (bit-truncation, exact).
__device__ __forceinline__ void split3(float v, unsigned short& s1,
                                       unsigned short& s2, unsigned short& s3) {
    const unsigned u1 = __float_as_uint(v) & 0xFFFF0000u;
    const float r1 = v - __uint_as_float(u1);
    const unsigned u2 = __float_as_uint(r1) & 0xFFFF0000u;
    const float r2 = r1 - __uint_as_float(u2);
    s1 = (unsigned short)(u1 >> 16);
    s2 = (unsigned short)(u2 >> 16);
    s3 = (unsigned short)(__float_as_uint(r2) >> 16);
}

// LDS A-plane addressing (halves): row = halo voxel (32 halves), 16B-slot XOR
// swizzle: slot(v,chunk) = (4v+chunk) ^ (v&7) -> 2-way max on write & read.
__device__ __forceinline__ int lds_a_off(int v, int chunk) {
    return ((v << 5) + (chunk << 3)) ^ ((v & 7) << 3);
}

// ---------------------------------------------------------------------------
// Fused weight 3-split for all three convs:
// w[oc][128][27] fp32 -> 3 planes of [27][4kb][4kc][OC][8] bf16.
__global__ __launch_bounds__(256) void wsplit_all(const float* __restrict__ wb,
                                                  const float* __restrict__ wo,
                                                  const float* __restrict__ wsd,
                                                  unsigned short* __restrict__ WB,
                                                  unsigned short* __restrict__ WO,
                                                  unsigned short* __restrict__ WS) {
    int blk = blockIdx.x;
    const float* src; unsigned short* dst; int OC;
    if (blk < 1728)      { src = wb;  dst = WB; OC = 128; }
    else if (blk < 2592) { src = wo;  dst = WO; OC = 64; blk -= 1728; }
    else                 { src = wsd; dst = WS; OC = 64; blk -= 2592; }
    const int i = blk * 256 + threadIdx.x;
    const int PS = OC * 3456;
    if (i >= PS) return;
    const int ko = i & 7;
    const int oc = (i >> 3) % OC;
    const int rest = (i >> 3) / OC;      // (t*4+kb)*4 + kc
    const int kc = rest & 3;
    const int kbt = rest >> 2;           // t*4+kb
    const int kb = kbt & 3, t = kbt >> 2;
    const int ic = kb * 32 + kc * 8 + ko;
    const float v = src[((size_t)oc * 128 + ic) * 27 + t];
    unsigned short s1, s2, s3;
    split3(v, s1, s2, s3);
    dst[i] = s1; dst[i + PS] = s2; dst[i + 2 * PS] = s3;
}

// ---------------------------------------------------------------------------
// occ2 block role (1024 thr): mask conv 64->2 as logit-DIFF over the ring.
// Tile 4a x 4b x 16z = 256 vox; halo 648 rows; 2 x 32-ic rounds.
__device__ void occ2_role(const float* __restrict__ HR,
                          const float* __restrict__ w,
                          const float* __restrict__ b,
                          unsigned char* __restrict__ mask,
                          int bx2raw, int sp_base, unsigned short* smraw) {
    const int grp = bx2raw >> 8;               // slab offset within this dispatch
    const int r   = bx2raw & 255;
    const int bx  = (r & 7) * 32 + (r >> 3);   // XCD swizzle within 256
    const int sp  = sp_base + grp;

    float* hl  = (float*)smraw;                // [648][36]  93312 B
    float* wl  = hl + 648 * 36;                // [1728]
    float* red = wl + 1728;                    // [4][260]

    const int tid = threadIdx.x;
    for (int i = tid; i < 1728; i += 1024) wl[i] = w[1728 + i] - w[i];

    const int a0 = sp * 32 + (bx >> 5) * 4;
    const int b0 = (bx & 31) * 4;
    const int g = tid >> 8, v = tid & 255;
    const int a_l = v >> 6, b_l = (v >> 4) & 3, z = v & 15;

    float acc0 = 0.f, acc1 = 0.f;
    #pragma unroll 1
    for (int half = 0; half < 2; ++half) {
        __syncthreads();
        for (int i = tid; i < 5184; i += 1024) {
            const int q4 = i / 648;
            const int hv = i - q4 * 648;
            const int col = hv / 18;
            const int zz  = hv - col * 18;
            const int ha  = col / 6;
            const int hb  = col - ha * 6;
            const int a = a0 + ha - 1;
            const int bb = b0 + hb - 1;
            const int zq = zz - 1;
            f32x4 val = {0.f, 0.f, 0.f, 0.f};
            if (((unsigned)a < 128u) && ((unsigned)bb < 128u) && ((unsigned)zq < 16u)) {
                const int q = a * 2048 + bb * 16 + zq;
                const int rc = ((a >> 5) & (NRING - 1)) * SLAB + (q & (SLAB - 1));
                const int ic0 = half * 32 + q4 * 4;
                #pragma unroll
                for (int j = 0; j < 4; ++j)
                    val[j] = HR[(size_t)(ic0 + j) * (NRING * SLAB) + rc];
            }
            *(f32x4*)(hl + hv * 36 + q4 * 4) = val;
        }
        __syncthreads();
        #pragma unroll 1
        for (int t = 0; t < 27; ++t) {
            const int ta = t / 9, tb = (t / 3) % 3, tz = t % 3;
            const int vt = ((a_l + ta) * 6 + b_l + tb) * 18 + z + tz;
            #pragma unroll
            for (int j = 0; j < 8; j += 2) {
                const int icl = g * 8 + j;
                const int ic = half * 32 + icl;
                acc0 = fmaf(hl[vt * 36 + icl],     wl[ic * 27 + t],       acc0);
                acc1 = fmaf(hl[vt * 36 + icl + 1], wl[(ic + 1) * 27 + t], acc1);
            }
        }
    }
    red[g * 260 + v] = acc0 + acc1;
    __syncthreads();
    if (g == 0) {
        float t0 = b[1] - b[0];
        #pragma unroll
        for (int k = 0; k < 4; ++k) t0 += red[k * 260 + v];
        mask[(a0 + a_l) * 2048 + (b0 + b_l) * 16 + z] = (t0 > 0.f) ? 1 : 0;
    }
}

// ---------------------------------------------------------------------------
// fp32-grade 3x3x3 conv via bf16-split 16x16x32 MFMA (R15 structure).
// PROD=6: 3 planes (mask path). PROD=3: 2 planes (post-mask path).
// FUSEOCC2: blocks >= occ1_grid run the occ2 mask role instead.
// Tap loop unroll 1 -- REGION WIDENING SPILLS (R13 full unroll: FETCH 1.5GB;
// R18 unroll 2: FETCH 729MB). Do not re-unroll.
template<int OC, int PROD, int AQ, bool PREMUL, bool LEAKY, int RING,
         bool FUSESSC, bool FUSEOCC2>
__global__ __launch_bounds__(AQ * 256, 1) void conv3s(const float* __restrict__ src,
                                              const float* __restrict__ prob,
                                              const unsigned short* __restrict__ W,
                                              const float* __restrict__ bias,
                                              float* __restrict__ out,
                                              const float* __restrict__ wssc,
                                              const float* __restrict__ bssc,
                                              unsigned char* __restrict__ maskp,
                                              int occ1_grid, int sp_base,
                                              int ablk_base) {
    constexpr int THREADS = AQ * 256;
    constexpr int NPL = (PROD == 6) ? 3 : 2;
    constexpr int HROWS = (AQ + 2) * 108;          // halo rows
    constexpr int PLH = HROWS * 32;                // plane size in halves
    constexpr int VOXT = AQ * 64;                  // output voxels per block
    constexpr int NITEM = HROWS * 4;               // staging items (row x ic-oct)
    constexpr int PFI = (NITEM + THREADS - 1) / THREADS;
    constexpr int EPIH = OC * (VOXT + 1) * 2;      // epilogue halves
    constexpr int SMH = (NPL * PLH > EPIH) ? NPL * PLH : EPIH;
    __shared__ __align__(16) unsigned short smraw[SMH];
    unsigned short* sm0 = smraw;
    unsigned short* sm1 = smraw + PLH;
    unsigned short* sm2 = smraw + (NPL - 1) * PLH; // ==sm1 when NPL==2 (unused)

    if (FUSEOCC2 && (int)blockIdx.x >= occ1_grid) {
        occ2_role(out, wssc, bssc, maskp, (int)blockIdx.x - occ1_grid,
                  sp_base, smraw);
        return;
    }

    const int tid = threadIdx.x;
    // bijective XCD swizzle over the conv-role grid
    const int cg = FUSEOCC2 ? occ1_grid : (int)gridDim.x;
    const int cpx = cg >> 3;
    const int bx = ((int)blockIdx.x & 7) * cpx + ((int)blockIdx.x >> 3);

    const int ablkA = ablk_base + (bx >> 5);       // AQ-a-row tile index
    const int b0    = (bx & 31) * 4;
    const int vbase = ablkA * (AQ * 2048) + b0 * 16;

    const int w = tid >> 6, l = tid & 63;
    const int lo16 = l & 15, hi4 = l >> 4;
    const int wo = w & 3, wm = w >> 2;
    constexpr int NF = OC / 64;                    // 128 -> 2, 64 -> 1
    constexpr int PS = OC * 3456;
    const int oc_off = wo * (16 * NF);

    f32x4 acc[4][NF];
    #pragma unroll
    for (int nf = 0; nf < NF; ++nf) {
        const float bv = bias[oc_off + nf * 16 + lo16];
        #pragma unroll
        for (int mf = 0; mf < 4; ++mf) acc[mf][nf] = f32x4{bv, bv, bv, bv};
    }

    // ---- prefetch registers (issue-early / write-late pipeline) ----
    float pf[PFI][8];
    float pfpm[PFI];

    #define PREFETCH(KB)                                                          \
        _Pragma("unroll")                                                         \
        for (int it = 0; it < PFI; ++it) {                                        \
            const int i = tid + it * THREADS;                                     \
            _Pragma("unroll")                                                     \
            for (int j = 0; j < 8; ++j) pf[it][j] = 0.f;                          \
            pfpm[it] = 1.f;                                                       \
            if (i < NITEM) {                                                      \
                const int q8 = i / HROWS;                                         \
                const int v  = i - q8 * HROWS;                                    \
                const int col = v / 18;                                           \
                const int zz  = v - col * 18;                                     \
                const int ha  = col / 6;                                          \
                const int hb  = col - ha * 6;                                     \
                const int a = ablkA * AQ + ha - 1;                                \
                const int b = b0 + hb - 1;                                        \
                const int z = zz - 1;                                             \
                if (((unsigned)a < 128u) && ((unsigned)b < 128u) &&               \
                    ((unsigned)z < 16u)) {                                        \
                    const int q = a * 2048 + b * 16 + z;                          \
                    const float* sp = src + (size_t)((KB) * 32 + q8 * 8) * NVOX + q; \
                    _Pragma("unroll")                                             \
                    for (int j = 0; j < 8; ++j) pf[it][j] = sp[(size_t)j * NVOX]; \
                    if (PREMUL) pfpm[it] = 1.f + prob[q];                         \
                }                                                                 \
            }                                                                     \
        }

    PREFETCH(0)

    #pragma unroll 1
    for (int kb = 0; kb < 4; ++kb) {
        __syncthreads();
        // write-late: split3 + swizzled b128 ds_write of the prefetched tile
        #pragma unroll
        for (int it = 0; it < PFI; ++it) {
            const int i = tid + it * THREADS;
            if (i < NITEM) {
                const int q8 = i / HROWS;
                const int v  = i - q8 * HROWS;
                s16x8 t1, t2, t3;
                #pragma unroll
                for (int j = 0; j < 8; ++j) {
                    float f = pf[it][j];
                    if (PREMUL) f *= pfpm[it];
                    unsigned short s1, s2, s3;
                    split3(f, s1, s2, s3);
                    t1[j] = (short)s1; t2[j] = (short)s2; t3[j] = (short)s3;
                }
                const int off = lds_a_off(v, q8);
                *(s16x8*)(sm0 + off) = t1;
                *(s16x8*)(sm1 + off) = t2;
                if (NPL == 3) *(s16x8*)(sm2 + off) = t3;
            }
        }
        if (kb < 3) PREFETCH(kb + 1)
        __syncthreads();

        #pragma unroll 1
        for (int ta = 0; ta < 3; ++ta) {
            #pragma unroll 1
            for (int tz = 0; tz < 3; ++tz) {
                // 6 shared A-fragments (s = mf+tb) for this wave's a-row
                bf16x8 A1[6], A2[6], A3[6];
                #pragma unroll
                for (int s = 0; s < 6; ++s) {
                    const int v = ((wm + ta) * 6 + s) * 18 + lo16 + tz;
                    const int ao = lds_a_off(v, hi4);
                    A1[s] = *(const bf16x8*)(sm0 + ao);
                    A2[s] = *(const bf16x8*)(sm1 + ao);
                    if (PROD == 6) A3[s] = *(const bf16x8*)(sm2 + ao);
                }
                #pragma unroll
                for (int tb = 0; tb < 3; ++tb) {
                    const int t = ta * 9 + tb * 3 + tz;
                    bf16x8 b1[NF], b2[NF], b3[NF];
                    #pragma unroll
                    for (int nf = 0; nf < NF; ++nf) {
                        const size_t wb = (((size_t)(t * 4 + kb) * 4 + hi4) * OC
                                           + oc_off + nf * 16 + lo16) * 8;
                        b1[nf] = *(const bf16x8*)(W + wb);
                        b2[nf] = *(const bf16x8*)(W + PS + wb);
                        if (PROD == 6) b3[nf] = *(const bf16x8*)(W + 2 * PS + wb);
                    }
                    #pragma unroll
                    for (int mf = 0; mf < 4; ++mf) {
                        const int s = mf + tb;          // static after unroll
                        #pragma unroll
                        for (int nf = 0; nf < NF; ++nf) {
                            acc[mf][nf] = mfma16(A1[s], b1[nf], acc[mf][nf]);
                            acc[mf][nf] = mfma16(A1[s], b2[nf], acc[mf][nf]);
                            acc[mf][nf] = mfma16(A2[s], b1[nf], acc[mf][nf]);
                        }
                        if (PROD == 6) {
                            #pragma unroll
                            for (int nf = 0; nf < NF; ++nf) {
                                acc[mf][nf] = mfma16(A2[s], b2[nf], acc[mf][nf]);
                                acc[mf][nf] = mfma16(A1[s], b3[nf], acc[mf][nf]);
                                acc[mf][nf] = mfma16(A3[s], b1[nf], acc[mf][nf]);
                            }
                        }
                    }
                }
            }
        }
    }
    #undef PREFETCH

    // epilogue: leaky -> ldsT[oc][VOXT+1] transpose (stride odd -> conflict-free)
    __syncthreads();
    float* ldsT = (float*)smraw;
    #pragma unroll
    for (int mf = 0; mf < 4; ++mf)
        #pragma unroll
        for (int nf = 0; nf < NF; ++nf) {
            const int oc = oc_off + nf * 16 + lo16;
            #pragma unroll
            for (int r = 0; r < 4; ++r) {
                float vv = acc[mf][nf][r];
                if (LEAKY) vv = leaky(vv);
                // C/D 16x16: col=l&15(oc), row=(l>>4)*4+r; tile vox = wm*64+mf*16+row
                ldsT[oc * (VOXT + 1) + wm * 64 + mf * 16 + hi4 * 4 + r] = vv;
            }
        }
    __syncthreads();
    if (FUSESSC) {
        // 1x1 conv 64->20 from LDS, write [20][NVOX]
        for (int i = tid; i < 20 * VOXT; i += THREADS) {
            const int tv = i % VOXT;
            const int o = i / VOXT;         // wave-uniform (VOXT multiple of 64)
            float acc2 = bssc[o];
            #pragma unroll
            for (int ic = 0; ic < 64; ++ic)
                acc2 = fmaf(ldsT[ic * (VOXT + 1) + tv], wssc[o * 64 + ic], acc2);
            out[(size_t)o * NVOX + vbase + (tv >> 6) * 2048 + (tv & 63)] = acc2;
        }
    } else {
        int obase;
        if (RING == 0) obase = vbase;
        else           obase = ((vbase >> 16) & (NRING - 1)) * SLAB + (vbase & (SLAB - 1));
        const size_t outN = (RING == 0) ? (size_t)NVOX : (size_t)(NRING * SLAB);
        for (int i = tid; i < OC * VOXT; i += THREADS) {
            const int oc = i / VOXT, tv = i % VOXT;
            out[(size_t)oc * outN + obase + (tv >> 6) * 2048 + (tv & 63)] =
                ldsT[oc * (VOXT + 1) + tv];
        }
    }
}

// ---------------------------------------------------------------------------
// Per-voxel MLP prior + masked select, in-place over x ([128][N] f32)
__global__ __launch_bounds__(256) void mlp_vox(float* __restrict__ x,
                                               const float* __restrict__ w1,
                                               const float* __restrict__ b1,
                                               const float* __restrict__ g,
                                               const float* __restrict__ beta,
                                               const float* __restrict__ w2,
                                               const float* __restrict__ b2,
                                               const unsigned char* __restrict__ mask) {
    const int p = blockIdx.x * 256 + threadIdx.x;
    float h[64];
    #pragma unroll
    for (int j = 0; j < 64; ++j) h[j] = b1[j];
    #pragma unroll 1
    for (int c = 0; c < 128; ++c) {
        const float xv = x[(size_t)c * NVOX + p];
        #pragma unroll
        for (int j = 0; j < 64; ++j) h[j] = fmaf(xv, w1[c * 64 + j], h[j]);
    }
    float mu = 0.f;
    #pragma unroll
    for (int j = 0; j < 64; ++j) mu += h[j];
    mu *= (1.f / 64.f);
    float var = 0.f;
    #pragma unroll
    for (int j = 0; j < 64; ++j) { const float d = h[j] - mu; var = fmaf(d, d, var); }
    var *= (1.f / 64.f);
    const float rs = rsqrtf(var + 1e-5f);
    #pragma unroll
    for (int j = 0; j < 64; ++j) h[j] = leaky((h[j] - mu) * rs * g[j] + beta[j]);

    const bool m = mask[p] != 0;
    #pragma unroll 1
    for (int c = 0; c < 128; ++c) {
        float pr = b2[c];
        #pragma unroll
        for (int j = 0; j < 64; ++j) pr = fmaf(h[j], w2[j * 128 + c], pr);
        const size_t idx = (size_t)c * NVOX + p;
        x[idx] = m ? x[idx] : pr;
    }
}

// ---------------------------------------------------------------------------
extern "C" void kernel_launch(void* const* d_in, const int* in_sizes, int n_in,
                              void* d_out, int out_size, void* d_ws, size_t ws_size,
                              hipStream_t stream) {
    const float* x3d    = (const float*)d_in[0];
    const float* prob   = (const float*)d_in[1];
    const float* w_bot  = (const float*)d_in[2];
    const float* b_bot  = (const float*)d_in[3];
    const float* w_occ1 = (const float*)d_in[4];
    const float* b_occ1 = (const float*)d_in[5];
    const float* w_occ2 = (const float*)d_in[6];
    const float* b_occ2 = (const float*)d_in[7];
    const float* w_mlp1 = (const float*)d_in[8];
    const float* b_mlp1 = (const float*)d_in[9];
    const float* ln_g   = (const float*)d_in[10];
    const float* ln_b   = (const float*)d_in[11];
    const float* w_mlp2 = (const float*)d_in[12];
    const float* b_mlp2 = (const float*)d_in[13];
    const float* w_sdb  = (const float*)d_in[14];
    const float* b_sdb  = (const float*)d_in[15];
    const float* w_ssc  = (const float*)d_in[16];
    const float* b_ssc  = (const float*)d_in[17];

    char* ws = (char*)d_ws;
    float* X32 = (float*)(ws);                                 // [128][N] f32, 134.2 MB
    float* HR  = (float*)(ws + 134217728);                     // [64][4*SLAB] f32 ring, 67.1 MB
    unsigned short* WB3 = (unsigned short*)(ws + 201326592);   // 2654208 B
    unsigned short* W13 = (unsigned short*)(ws + 203980800);   // 1327104 B
    unsigned short* WS3 = (unsigned short*)(ws + 205307904);   // 1327104 B
    unsigned char* mask = (unsigned char*)(ws + 206635008);    // 262144 B

    const dim3 blk(256);
    const dim3 blk10(1024);

    // fused weight split (1 dispatch)
    wsplit_all<<<3456, blk, 0, stream>>>(w_bot, w_occ1, w_sdb, WB3, W13, WS3);

    // 1) bottleneck conv 128->128 (6-product, AQ=4) : x3d -> X32
    conv3s<128, 6, 4, false, false, 0, false, false><<<1024, blk10, 0, stream>>>(
        x3d, nullptr, WB3, b_bot, X32, nullptr, nullptr, nullptr, 0, 0, 0);

    // 2/3) occ conv1 (premul, 6-product, AQ=4) per slab into 4-slot ring;
    // occ2(s-2) blocks fused into occ1(s) dispatches; tail handles slabs 2,3.
    for (int s = 0; s < NSLAB; ++s) {
        const int grid = (s >= 2) ? 512 : 256;
        conv3s<64, 6, 4, true, true, 2, false, true><<<grid, blk10, 0, stream>>>(
            X32, prob, W13, b_occ1, HR, w_occ2, b_occ2, mask, 256, s - 2, 8 * s);
    }
    // tail: occ2 for slabs 2 and 3 in one dispatch (all blocks occ2 role)
    conv3s<64, 6, 4, true, true, 2, false, true><<<512, blk10, 0, stream>>>(
        X32, prob, W13, b_occ1, HR, w_occ2, b_occ2, mask, 0, 2, 0);

    // 4) MLP prior + masked select, in-place on X32
    mlp_vox<<<1024, blk, 0, stream>>>(X32, w_mlp1, b_mlp1, ln_g, ln_b, w_mlp2, b_mlp2, mask);

    // 5/6) SDB conv (3-product, AQ=4) + fused SSC head -> d_out [20][N] f32
    conv3s<64, 3, 4, false, true, 0, true, false><<<1024, blk10, 0, stream>>>(
        X32, nullptr, WS3, b_sdb, (float*)d_out, w_ssc, b_ssc, nullptr, 0, 0, 0);
}